// Round 10
// baseline (56.873 us; speedup 1.0000x reference)
//
#include <hip/hip_runtime.h>

// MQCNN layer — closed-form reduction.
//
// Math: H⊗4 on wires 0-3 → 16 diagonal branches b∈{0,1}^4. All encoding
// gates are controlled-RY on wire 4 (same axis ⇒ angles add per branch).
// The conv block (H on 5, 24 ctrl-U3 on wire 6) never acts on wire 4, so
// the wire-4 marginal — and hence <Z4> — is unchanged by it. U3_w drops out.
//   z = (1/16) Σ_b cos(θ_b),  θ_b = Σ_{i: ctrls(i)⊆b} pv[i]
// Grouped by control set (ENC table):
//   A=pv0+pv4+pv8, t01=pv3, t02=pv1+pv6, t03=pv5+pv10, t13=pv2+pv11, t23=pv7+pv9
// NOTE: pair (1,2) never occurs as a control set, so SIX branches
// (∅,{0},{1},{2},{3},{1,2}) have θ=A.

__global__ __launch_bounds__(256) void mqcnn_kernel(const float* __restrict__ x,
                                                    float* __restrict__ out,
                                                    int n) {
    int p = blockIdx.x * blockDim.x + threadIdx.x;
    if (p >= n) return;

    // out layout: [B=32][1][h=64][w=64] ; p = b*4096 + j*64 + k
    int k = p & 63;
    int j = (p >> 6) & 63;
    int b = p >> 12;

    // x layout: [32][3][128][128]
    const float* xb = x + (size_t)b * (3 * 128 * 128);
    const float* x0 = xb;                 // channel 0
    const float* x1 = xb + 128 * 128;     // channel 1
    const float* x2 = xb + 2 * 128 * 128; // channel 2

    const int r0 = 2 * j;
    const int r1 = 2 * j + 1;
    const int c  = 2 * k;                 // even → float2 loads are 8B-aligned

    // pv[c*4 + dj*2 + dk] = x[b, c, 2j+dj, 2k+dk]
    float2 a0 = *(const float2*)(x0 + r0 * 128 + c);   // pv0, pv1
    float2 a1 = *(const float2*)(x0 + r1 * 128 + c);   // pv2, pv3
    float2 b0 = *(const float2*)(x1 + r0 * 128 + c);   // pv4, pv5
    float2 b1 = *(const float2*)(x1 + r1 * 128 + c);   // pv6, pv7
    float2 c0 = *(const float2*)(x2 + r0 * 128 + c);   // pv8, pv9
    float2 c1 = *(const float2*)(x2 + r1 * 128 + c);   // pv10, pv11

    float A   = a0.x + b0.x + c0.x;   // always-on: pv0+pv4+pv8
    float t01 = a1.y;                 // pv3
    float t02 = a0.y + b1.x;          // pv1+pv6
    float t03 = b0.y + c1.x;          // pv5+pv10
    float t13 = a1.x + c1.y;          // pv2+pv11
    float t23 = b1.y + c0.y;          // pv7+pv9

    // 16 branches: 6 have θ=A (incl. {1,2} — no (1,2) control pair exists);
    // the other 10 are the distinct sums below.
    float z = 6.0f * cosf(A)
            + cosf(A + t01)
            + cosf(A + t02)
            + cosf(A + t03)
            + cosf(A + t13)
            + cosf(A + t23)
            + cosf(A + t01 + t02)
            + cosf(A + t01 + t03 + t13)
            + cosf(A + t02 + t03 + t23)
            + cosf(A + t13 + t23)
            + cosf(A + t01 + t02 + t03 + t13 + t23);

    out[p] = z * 0.0625f;
}

extern "C" void kernel_launch(void* const* d_in, const int* in_sizes, int n_in,
                              void* d_out, int out_size, void* d_ws, size_t ws_size,
                              hipStream_t stream) {
    const float* x = (const float*)d_in[0];
    // d_in[1] (U3_w) is provably irrelevant to the output — see header comment.
    float* out = (float*)d_out;

    const int n = out_size;               // 32*1*64*64 = 131072
    dim3 block(256);
    dim3 grid((n + 255) / 256);           // 512 blocks
    hipLaunchKernelGGL(mqcnn_kernel, grid, block, 0, stream, x, out, n);
}

// Round 18
// 56.317 us; speedup vs baseline: 1.0099x; 1.0099x over previous
//
#include <hip/hip_runtime.h>

// MQCNN layer — closed-form reduction.
//
// Math: H⊗4 on wires 0-3 → 16 diagonal branches b∈{0,1}^4. All encoding
// gates are controlled-RY on wire 4 (same axis ⇒ angles add per branch).
// The conv block (H on 5, 24 ctrl-U3 on wire 6) never acts on wire 4, so
// the wire-4 marginal — and hence <Z4> — is unchanged by it. U3_w drops out.
//   z = (1/16) Σ_b cos(θ_b),  θ_b = Σ_{i: ctrls(i)⊆b} pv[i]
// Grouped by control set (ENC table):
//   A=pv0+pv4+pv8, t01=pv3, t02=pv1+pv6, t03=pv5+pv10, t13=pv2+pv11, t23=pv7+pv9
// NOTE: pair (1,2) never occurs as a control set, so SIX branches
// (∅,{0},{1},{2},{3},{1,2}) have θ=A.
//
// R10→R11: cosf → __cosf (v_cos_f32 path). All args bounded: pv∈[0,π],
// max sum = 12 terms ≤ 12π ≈ 37.7 rad ≈ 6 revolutions — inside v_cos_f32's
// valid domain; added error ~1e-6 vs the 3.9e-3 absmax margin.

__global__ __launch_bounds__(256) void mqcnn_kernel(const float* __restrict__ x,
                                                    float* __restrict__ out,
                                                    int n) {
    int p = blockIdx.x * blockDim.x + threadIdx.x;
    if (p >= n) return;

    // out layout: [B=32][1][h=64][w=64] ; p = b*4096 + j*64 + k
    int k = p & 63;
    int j = (p >> 6) & 63;
    int b = p >> 12;

    // x layout: [32][3][128][128]
    const float* xb = x + (size_t)b * (3 * 128 * 128);
    const float* x0 = xb;                 // channel 0
    const float* x1 = xb + 128 * 128;     // channel 1
    const float* x2 = xb + 2 * 128 * 128; // channel 2

    const int r0 = 2 * j;
    const int r1 = 2 * j + 1;
    const int c  = 2 * k;                 // even → float2 loads are 8B-aligned

    // pv[c*4 + dj*2 + dk] = x[b, c, 2j+dj, 2k+dk]
    float2 a0 = *(const float2*)(x0 + r0 * 128 + c);   // pv0, pv1
    float2 a1 = *(const float2*)(x0 + r1 * 128 + c);   // pv2, pv3
    float2 b0 = *(const float2*)(x1 + r0 * 128 + c);   // pv4, pv5
    float2 b1 = *(const float2*)(x1 + r1 * 128 + c);   // pv6, pv7
    float2 c0 = *(const float2*)(x2 + r0 * 128 + c);   // pv8, pv9
    float2 c1 = *(const float2*)(x2 + r1 * 128 + c);   // pv10, pv11

    float A   = a0.x + b0.x + c0.x;   // always-on: pv0+pv4+pv8
    float t01 = a1.y;                 // pv3
    float t02 = a0.y + b1.x;          // pv1+pv6
    float t03 = b0.y + c1.x;          // pv5+pv10
    float t13 = a1.x + c1.y;          // pv2+pv11
    float t23 = b1.y + c0.y;          // pv7+pv9

    // 16 branches: 6 have θ=A (incl. {1,2} — no (1,2) control pair exists);
    // the other 10 are the distinct sums below.
    float z = 6.0f * __cosf(A)
            + __cosf(A + t01)
            + __cosf(A + t02)
            + __cosf(A + t03)
            + __cosf(A + t13)
            + __cosf(A + t23)
            + __cosf(A + t01 + t02)
            + __cosf(A + t01 + t03 + t13)
            + __cosf(A + t02 + t03 + t23)
            + __cosf(A + t13 + t23)
            + __cosf(A + t01 + t02 + t03 + t13 + t23);

    out[p] = z * 0.0625f;
}

extern "C" void kernel_launch(void* const* d_in, const int* in_sizes, int n_in,
                              void* d_out, int out_size, void* d_ws, size_t ws_size,
                              hipStream_t stream) {
    const float* x = (const float*)d_in[0];
    // d_in[1] (U3_w) is provably irrelevant to the output — see header comment.
    float* out = (float*)d_out;

    const int n = out_size;               // 32*1*64*64 = 131072
    dim3 block(256);
    dim3 grid((n + 255) / 256);           // 512 blocks
    hipLaunchKernelGGL(mqcnn_kernel, grid, block, 0, stream, x, out, n);
}